// Round 16
// baseline (375.589 us; speedup 1.0000x reference)
//
#include <hip/hip_runtime.h>

#define HH 256
#define WW 256
#define NPIX (HH*WW)
#define LL 16
#define NL (NPIX*LL)
#define PP 136
#define PP2 (PP*2)
#define NBLK (NPIX/32)   // 2048

typedef _Float16 half_t;
typedef __attribute__((ext_vector_type(8))) _Float16 half8;
typedef __attribute__((ext_vector_type(2))) _Float16 half2h;

// constants (double-evaluated, cast to float -- matches JAX weak-typed scalars)
static constexpr float SIGMAP_F = (float)((1.0/256.0)/(3.0+16.0)); // res/(3+l)
static constexpr float TAUU_F   = (float)((1.0/256.0)/6.0);        // res/6
static constexpr float TAU_F    = (float)(1.0/36.0);               // 1/(2+136/4)

__device__ __forceinline__ float clampf(float x, float lo, float hi){
    return fminf(fmaxf(x, lo), hi);
}
__device__ __forceinline__ half8 h8zero() {
    half8 v;
    #pragma unroll
    for (int i = 0; i < 8; ++i) v[i] = (half_t)0.0f;
    return v;
}
__device__ __forceinline__ half2h h2zero() {
    half2h v;
    v[0] = (half_t)0.0f; v[1] = (half_t)0.0f;
    return v;
}

// ---------------- prox for one (pixel, z-pair): 2 z's ------------------------
// PM 0 = it0 (all state analytically zero; reads ONLY f), PM 1 = steady.
// 2-z granularity spreads prox over ALL 512 threads (520 items; threads 0-7
// take the 8 west-halo extras) -- prox is the VALU-heaviest phase (divergent
// cubic: cbrt + acos/cos both execute under mixed exec masks).
template<int PM>
__device__ __forceinline__ void prox_q2(const float* __restrict__ f, int np, int z0,
    const half_t* __restrict__ ubOld, const half_t* __restrict__ pxOld,
    const half_t* __restrict__ ptOld, const half_t* __restrict__ msOld,
    half2h& o0, half2h& o1, half2h& opt)
{
    int ip = np >> 8, jp = np & (WW-1);
    bool iok = (ip < HH-1), jok = (jp < WW-1);
    size_t base = (size_t)np*LL + z0;
    float fv = f[np];

    float g0c = 0.0f, g1c = 0.0f;
    half2h ubv = h2zero(), ubi = h2zero(), ubj = h2zero();
    float ubn2 = 0.0f;
    half2h ms0v = h2zero(), ms1v = h2zero();
    half2h p0v  = h2zero(), p1v  = h2zero(), ptv = h2zero();
    if (PM == 0) {
        g0c = iok ? (f[np + WW] - fv) * 256.0f : 0.0f;
        g1c = jok ? (f[np + 1]  - fv) * 256.0f : 0.0f;
    } else {
        ubv = *reinterpret_cast<const half2h*>(ubOld + base);
        if (iok) ubi = *reinterpret_cast<const half2h*>(ubOld + base + (size_t)WW*LL);
        if (jok) ubj = *reinterpret_cast<const half2h*>(ubOld + base + LL);
        if (z0 < 14) ubn2 = (float)ubOld[base + 2];
        ms0v = *reinterpret_cast<const half2h*>(msOld + base);
        ms1v = *reinterpret_cast<const half2h*>(msOld + NL + base);
        p0v  = *reinterpret_cast<const half2h*>(pxOld + base);
        p1v  = *reinterpret_cast<const half2h*>(pxOld + NL + base);
        ptv  = *reinterpret_cast<const half2h*>(ptOld + base);
    }

    #pragma unroll
    for (int e = 0; e < 2; ++e) {
        int z = z0 + e;
        float ux0, ux1, ut;
        if (PM == 0) {
            ux0 = SIGMAP_F * g0c;
            ux1 = SIGMAP_F * g1c;
            ut  = 0.0f;
        } else {
            float ub = (float)ubv[e];
            float g0 = iok ? ((float)ubi[e] - ub) * 256.0f : 0.0f;
            float g1 = jok ? ((float)ubj[e] - ub) * 256.0f : 0.0f;
            float ubn = (e < 1) ? (float)ubv[1] : ubn2;
            float gt = (z < LL-1) ? (ubn - ub) * 16.0f : 0.0f;
            ux0 = (float)p0v[e] + SIGMAP_F * (g0 + (float)ms0v[e]);
            ux1 = (float)p1v[e] + SIGMAP_F * (g1 + (float)ms1v[e]);
            ut  = (float)ptv[e] + SIGMAP_F * gt;
        }

        float klf = (float)(z + 1) * 0.0625f - fv;
        float pen = 0.5f * klf * klf;            // lmbda = 0.5

        float n2 = ux0*ux0 + ux1*ux1;
        float B  = 0.25f * n2 - pen;
        bool mask = ut < B;

        float px0 = ux0, px1 = ux1, ptn = ut;
        if (mask) {
            float y    = ut + pen;
            float norm = sqrtf(n2);
            float a    = 0.5f * norm;
            float b    = (2.0f/3.0f) * (1.0f - 0.5f*y);
            float v;
            if (b < 0.0f) {
                float sb  = sqrtf(-b);
                float sb3 = sb*sb*sb;
                float dd  = (a - sb3)*(a + sb3);
                if (dd < 0.0f) {
                    float ratio = clampf(a / sb3, -1.0f, 1.0f);
                    v = 2.0f * sb * cosf(acosf(ratio) * (1.0f/3.0f));
                } else {
                    float c = cbrtf(a + sqrtf(dd));
                    v = (c == 0.0f) ? 0.0f : (c - b/c);
                }
            } else {
                float dd = a*a + b*b*b;          // >= 0
                float c  = cbrtf(a + sqrtf(dd));
                v = (c == 0.0f) ? 0.0f : (c - b/c);
            }
            if (norm == 0.0f) { px0 = 0.0f; px1 = 0.0f; }
            else              { float s = 2.0f*v/norm; px0 = s*ux0; px1 = s*ux1; }
            ptn = 0.25f*(px0*px0 + px1*px1) - pen;
        }
        o0[e]  = (half_t)px0;
        o1[e]  = (half_t)px1;
        opt[e] = (half_t)ptn;
    }
}

// element access helpers (k static under unroll)
#define PH(k)  ((k) < 8 ? (float)ph0[(k)] : (float)ph1[(k)-8])
#define PPV(k) ((k) < 8 ? (float)pp0[(k)] : (float)pp1[(k)-8])

// ---------------- s & mu update for one row set ------------------------------
// mu values are PRELOADED by the caller (hoisted before the prox phase so the
// 71 MB mu stream's latency hides under prox compute + barrier).
template<int H, int MODE>
__device__ __forceinline__ void do_set(int lane,
    half8 ph0, half8 ph1, half8 pp0, half8 pp1,
    half8 mCv0, half8 mCv1, float mCT,
    half8 mOv0, half8 mOv1, float mOT,
    half_t* __restrict__ muO, size_t vb, size_t vb1, size_t tailIx,
    float* __restrict__ part)
{
    // row totals (descending start): tsA = sum p[H..15], tsB = sum p[15-H..15]
    float tsA = 0.0f, tsB = 0.0f, tpA = 0.0f, tpB = 0.0f;
    #pragma unroll
    for (int k = H; k < 16; ++k) tsA += PH(k);
    #pragma unroll
    for (int k = 15-H; k < 16; ++k) tsB += PH(k);
    if (MODE >= 1) {
        #pragma unroll
        for (int k = H; k < 16; ++k) tpA += PPV(k);
        #pragma unroll
        for (int k = 15-H; k < 16; ++k) tpB += PPV(k);
    }

    half8 muo0, muo1;
    half_t muoT = (half_t)0.0f;
    float sA = 0.0f, sB = 0.0f;
    int q = 0;

    #pragma unroll
    for (int z = 15; z >= 0; --z) {
        float m = 0.0f;
        if (z >= H) {                      // task (H, z)
            float mn;
            if (MODE == 0) {
                mn = -TAU_F * tsA;
            } else {
                float mC, mO;
                if (q < 8)       { mC=(float)mCv0[q];   mO=(float)mOv0[q]; }
                else if (q < 16) { mC=(float)mCv1[q-8]; mO=(float)mOv1[q-8]; }
                else             { mC=mCT;              mO=mOT; }
                float sxp = (mC - mO) * 36.0f + tpA;
                float mx  = sxp - (2.0f*mC - mO);
                float mo  = __shfl_xor(mx, 1);
                float snorm = sqrtf(mx*mx + mo*mo);
                if (snorm > 25.6f) mx *= 0.1f / snorm;   // nu*H ; nu/snorm
                mn = mC + TAU_F*(mx - tsA);
            }
            if (q < 8)       muo0[q]   = (half_t)mn;
            else if (q < 16) muo1[q-8] = (half_t)mn;
            else             muoT      = (half_t)mn;
            sA += mn; m += sA; ++q;
        }
        if (z >= 15-H) {                   // task (15-H, z)
            float mn;
            if (MODE == 0) {
                mn = -TAU_F * tsB;
            } else {
                float mC, mO;
                if (q < 8)       { mC=(float)mCv0[q];   mO=(float)mOv0[q]; }
                else if (q < 16) { mC=(float)mCv1[q-8]; mO=(float)mOv1[q-8]; }
                else             { mC=mCT;              mO=mOT; }
                float sxp = (mC - mO) * 36.0f + tpB;
                float mx  = sxp - (2.0f*mC - mO);
                float mo  = __shfl_xor(mx, 1);
                float snorm = sqrtf(mx*mx + mo*mo);
                if (snorm > 25.6f) mx *= 0.1f / snorm;
                mn = mC + TAU_F*(mx - tsB);
            }
            if (q < 8)       muo0[q]   = (half_t)mn;
            else if (q < 16) muo1[q-8] = (half_t)mn;
            else             muoT      = (half_t)mn;
            sB += mn; m += sB; ++q;
        }
        if (z >= H+1)    tsA -= PH(z);
        if (z >= 15-H+1) tsB -= PH(z);
        if (MODE >= 1) {
            if (z >= H+1)    tpA -= PPV(z);
            if (z >= 15-H+1) tpB -= PPV(z);
        }
        part[H*1024 + z*64 + lane] = m;
    }

    *reinterpret_cast<half8*>(&muO[vb])  = muo0;
    *reinterpret_cast<half8*>(&muO[vb1]) = muo1;
    muO[tailIx] = muoT;
}

// ---------------- fused iteration kernel -------------------------------------
// MODE: 0 = it0 (state zero; nrj partials), 1 = it1 (muO poisoned, skip read),
// 2 = steady, 3 = LAST (phase A dead: skip all mu traffic + px/pt/ms writes).
// Load schedule: mu (71 MB, the dominant stream) + pp + u issue FIRST; their
// latency hides under the prox phase (all 512 threads) and the barrier.
template<int MODE>
__global__ __launch_bounds__(512, 4) void k_iter(
    const float* __restrict__ f,
    const half_t* __restrict__ pxOld, half_t* __restrict__ pxCur,
    const half_t* __restrict__ ptOld, half_t* __restrict__ ptCur,
    const half_t* __restrict__ ubOld, half_t* __restrict__ ubCur,
    const half_t* __restrict__ msOld, half_t* __restrict__ msCur,
    const half_t* __restrict__ muC, half_t* __restrict__ muO,
    float* __restrict__ u, float* __restrict__ out,
    float* __restrict__ nrjPartial)
{
    __shared__ float part[(MODE <= 2) ? 8192 : 1];   // 32 KB (unused at MODE 3)
    __shared__ __align__(16) half_t lp0[64][24];     // px0: own 0..31, north 32..63
    __shared__ __align__(16) half_t lp1[33][24];     // px1: own 0..31, west 32
    __shared__ __align__(16) half_t lpt[32][24];     // pt : own
    __shared__ float wsum[8];

    int tid = threadIdx.x;
    int b   = blockIdx.x;
    int n0  = b << 5;             // first owned pixel (32 consecutive, same row)
    int i0  = n0 >> 8;
    int j0  = n0 & (WW-1);

    int wv = tid >> 6, lane = tid & 63, pix = lane >> 1, d = lane & 1;
    int n  = n0 + pix;

    // -------- hoisted loads: mu (biggest stream) + pp + u, issued first ------
    size_t setbase = (size_t)wv * 17 * 2 * NPIX;
    size_t vb     = setbase + (size_t)n*16 + (size_t)d*8;
    size_t vb1    = vb + (size_t)16*NPIX;
    size_t tailIx = setbase + (size_t)32*NPIX + (size_t)n*2 + (size_t)d;
    half8 mCv0 = h8zero(), mCv1 = h8zero(), mOv0 = h8zero(), mOv1 = h8zero();
    float mCT = 0.0f, mOT = 0.0f;
    if (MODE == 1 || MODE == 2) {
        mCv0 = *reinterpret_cast<const half8*>(&muC[vb]);
        mCv1 = *reinterpret_cast<const half8*>(&muC[vb1]);
        mCT  = (float)muC[tailIx];
    }
    if (MODE == 2) {
        mOv0 = *reinterpret_cast<const half8*>(&muO[vb]);
        mOv1 = *reinterpret_cast<const half8*>(&muO[vb1]);
        mOT  = (float)muO[tailIx];
    }
    half8 pp0 = h8zero(), pp1 = h8zero();
    if (MODE == 1 || MODE == 2) {
        const half8* ppv = reinterpret_cast<const half8*>(pxOld + (size_t)d*NL + (size_t)n*LL);
        pp0 = ppv[0]; pp1 = ppv[1];
    }
    int t  = b*512 + tid;            // global (n,z): n2 = t>>4, z = t&15
    int z  = t & (LL-1);
    int n2 = t >> 4;
    int i2 = n2 >> 8;
    int j2 = n2 & (WW-1);
    float uo = (MODE == 0) ? f[n2] : u[t];

    // -------- prox phase: 520 2-z items over all 512 threads --------
    // item -> pl = item>>3 (pixel slot 0..64), z0 = (item&7)*2
    // pl<32: own; pl<64: north halo; pl==64: west halo (items 512..519)
    {
        auto prox_item = [&](int item) {
            int pl  = item >> 3;
            int z0v = (item & 7) << 1;
            int np; bool valid = true;
            if (pl < 32)      np = n0 + pl;
            else if (pl < 64) { np = n0 + (pl-32) - WW; valid = (i0 > 0); }
            else              { np = n0 - 1;            valid = (j0 > 0); }
            if (!valid) return;
            half2h o0, o1, opt;
            prox_q2<(MODE==0) ? 0 : 1>(f, np, z0v, ubOld, pxOld, ptOld, msOld, o0, o1, opt);
            if (pl < 64) *reinterpret_cast<half2h*>(&lp0[pl][z0v]) = o0;
            if (pl < 32) {
                *reinterpret_cast<half2h*>(&lp1[pl][z0v]) = o1;
                *reinterpret_cast<half2h*>(&lpt[pl][z0v]) = opt;
                if (MODE <= 2) {   // next iteration consumes these
                    *reinterpret_cast<half2h*>(pxCur + (size_t)np*LL + z0v)      = o0;
                    *reinterpret_cast<half2h*>(pxCur + NL + (size_t)np*LL + z0v) = o1;
                    *reinterpret_cast<half2h*>(ptCur + (size_t)np*LL + z0v)      = opt;
                }
            } else {
                *reinterpret_cast<half2h*>(&lp1[32][z0v]) = o1;
            }
        };
        prox_item(tid);
        if (tid < 8) prox_item(512 + tid);   // west-halo extras
    }

    __syncthreads();   // LDS px/pt visible

    // -------- phase A: s & mu (skipped entirely at MODE 3) --------
    if (MODE <= 2) {
        const half8* ls = (d == 0) ? reinterpret_cast<const half8*>(&lp0[pix][0])
                                   : reinterpret_cast<const half8*>(&lp1[pix][0]);
        half8 ph0 = ls[0], ph1 = ls[1];

        if      (wv == 0) do_set<0,MODE>(lane,ph0,ph1,pp0,pp1,mCv0,mCv1,mCT,mOv0,mOv1,mOT,muO,vb,vb1,tailIx,part);
        else if (wv == 1) do_set<1,MODE>(lane,ph0,ph1,pp0,pp1,mCv0,mCv1,mCT,mOv0,mOv1,mOT,muO,vb,vb1,tailIx,part);
        else if (wv == 2) do_set<2,MODE>(lane,ph0,ph1,pp0,pp1,mCv0,mCv1,mCT,mOv0,mOv1,mOT,muO,vb,vb1,tailIx,part);
        else if (wv == 3) do_set<3,MODE>(lane,ph0,ph1,pp0,pp1,mCv0,mCv1,mCT,mOv0,mOv1,mOT,muO,vb,vb1,tailIx,part);
        else if (wv == 4) do_set<4,MODE>(lane,ph0,ph1,pp0,pp1,mCv0,mCv1,mCT,mOv0,mOv1,mOT,muO,vb,vb1,tailIx,part);
        else if (wv == 5) do_set<5,MODE>(lane,ph0,ph1,pp0,pp1,mCv0,mCv1,mCT,mOv0,mOv1,mOT,muO,vb,vb1,tailIx,part);
        else if (wv == 6) do_set<6,MODE>(lane,ph0,ph1,pp0,pp1,mCv0,mCv1,mCT,mOv0,mOv1,mOT,muO,vb,vb1,tailIx,part);
        else              do_set<7,MODE>(lane,ph0,ph1,pp0,pp1,mCv0,mCv1,mCT,mOv0,mOv1,mOT,muO,vb,vb1,tailIx,part);

        __syncthreads();   // staged partials visible

        // -------- reduce partials over h, store fp16 musum --------
        #pragma unroll
        for (int r = 0; r < 2; ++r) {
            int z2    = (tid >> 6) + r*8;
            int inner = tid & 63;
            float s = 0.0f;
            #pragma unroll
            for (int hh = 0; hh < 8; ++hh) s += part[hh*1024 + z2*64 + inner];
            int d2 = inner & 1, pix2 = inner >> 1;
            msCur[(size_t)d2*NL + ((size_t)n0 + pix2)*LL + z2] = (half_t)s;
        }
    }

    // -------- phase B: primal u update (1 z per thread, all inputs LDS) ------
    {
        int pl2 = tid >> 4;
        float p0c = (float)lp0[pl2][z];
        float p1c = (float)lp1[pl2][z];
        float p0u = (i2 > 0) ? (float)lp0[32 + pl2][z] : 0.0f;
        float p1l = (j2 > 0) ? ((pl2 > 0) ? (float)lp1[pl2-1][z] : (float)lp1[32][z]) : 0.0f;
        float ptc = (float)lpt[pl2][z];
        float ptm = (z > 0) ? (float)lpt[pl2][z-1] : 0.0f;

        float d0 = ((i2 < HH-1) ? p0c : 0.0f) - p0u;
        float d1 = ((j2 < WW-1) ? p1c : 0.0f) - p1l;
        float dt = ((z < LL-1) ? ptc : 0.0f) - ptm;

        float Dv = uo + TAUU_F * ((d0 + d1) * 256.0f + dt * 16.0f);
        float un = clampf(Dv, 0.0f, 1.0f);
        if (z == 0)     un = 1.0f;
        if (z == LL-1)  un = 0.0f;
        if (MODE == 3) out[t] = un;      // final iteration: output directly
        else {
            u[t]     = un;
            ubCur[t] = (half_t)(2.0f*un - uo);
        }

        if (MODE == 0) {   // nrj only at it=0 (it%10==0 with repeats=10)
            float v = fabsf(un - uo);
            #pragma unroll
            for (int off = 32; off > 0; off >>= 1) v += __shfl_down(v, off);
            if ((tid & 63) == 0) wsum[wv] = v;
            __syncthreads();
            if (tid == 0) {
                float s = 0.0f;
                #pragma unroll
                for (int q2 = 0; q2 < 8; ++q2) s += wsum[q2];
                nrjPartial[b] = s;       // per-block partial; no atomics/zeroing
            }
        }
    }
}

// ---------------- tail: reduce nrj partials + scalars ------------------------
__global__ void k_final(const float* __restrict__ nrjPartial, float* __restrict__ out_tail)
{
    float s = 0.0f;
    for (int k = threadIdx.x; k < NBLK; k += 64) s += nrjPartial[k];
    #pragma unroll
    for (int off = 32; off > 0; off >>= 1) s += __shfl_down(s, off);
    if (threadIdx.x == 0) {
        out_tail[0] = s;
        out_tail[1] = s * (1.0f/1048576.0f);   // nrj / (H*W*1*l)
        out_tail[2] = 0.0f;
    }
}

extern "C" void kernel_launch(void* const* d_in, const int* in_sizes, int n_in,
                              void* d_out, int out_size, void* d_ws, size_t ws_size,
                              hipStream_t stream)
{
    const float* f = (const float*)d_in[0];
    float* out = (float*)d_out;

    char* w = (char*)d_ws;
    size_t off = 0;
    auto allocf = [&](size_t nfloats) {
        float* p = (float*)(w + off);
        off += nfloats * sizeof(float);
        return p;
    };
    auto alloch = [&](size_t nhalf) {
        half_t* p = (half_t*)(w + off);
        off += nhalf * sizeof(half_t);
        return p;
    };
    half_t* muA  = alloch((size_t)NPIX * PP2);   // 35.7 MB
    half_t* muB  = alloch((size_t)NPIX * PP2);   // 35.7 MB
    half_t* msA  = alloch(2*(size_t)NL);         // 4.2 MB
    half_t* msB  = alloch(2*(size_t)NL);
    half_t* pxA  = alloch(2*(size_t)NL);
    half_t* pxB  = alloch(2*(size_t)NL);
    half_t* ptA  = alloch((size_t)NL);           // 2.1 MB
    half_t* ptB  = alloch((size_t)NL);
    half_t* ubA  = alloch((size_t)NL);
    half_t* ubB  = alloch((size_t)NL);
    float*  u    = allocf((size_t)NL);           // 4.2 MB
    float*  nrjP = allocf(NBLK);
    (void)ws_size; (void)in_sizes; (void)n_in; (void)out_size;

    // No memset/init: it=0 fully specialized (MODE 0 reads only f); it=1 skips
    // the muO read (poisoned buffer fully overwritten at it=0/1); all other
    // buffers' first access is a write. nrj via per-block partials.
    half_t *pxO = pxA, *pxC = pxB;
    half_t *ptO = ptA, *ptC = ptB;
    half_t *ubO = ubA, *ubC = ubB;
    half_t *msO = msA, *msC = msB;
    half_t *mC  = muA, *mO  = muB;
    for (int it = 0; it < 10; ++it) {
        if (it == 0)
            k_iter<0><<<NBLK, 512, 0, stream>>>(f, pxO, pxC, ptO, ptC, ubO, ubC,
                                                msO, msC, mC, mO, u, out, nrjP);
        else if (it == 1)
            k_iter<1><<<NBLK, 512, 0, stream>>>(f, pxO, pxC, ptO, ptC, ubO, ubC,
                                                msO, msC, mC, mO, u, out, nrjP);
        else if (it < 9)
            k_iter<2><<<NBLK, 512, 0, stream>>>(f, pxO, pxC, ptO, ptC, ubO, ubC,
                                                msO, msC, mC, mO, u, out, nrjP);
        else
            k_iter<3><<<NBLK, 512, 0, stream>>>(f, pxO, pxC, ptO, ptC, ubO, ubC,
                                                msO, msC, mC, mO, u, out, nrjP);
        { half_t* tmp = pxO; pxO = pxC; pxC = tmp; }
        { half_t* tmp = ptO; ptO = ptC; ptC = tmp; }
        { half_t* tmp = ubO; ubO = ubC; ubC = tmp; }
        { half_t* tmp = msO; msO = msC; msC = tmp; }
        { half_t* tmp = mC;  mC  = mO;  mO  = tmp; }   // mO-buffer holds mu_k
    }

    k_final<<<1, 64, 0, stream>>>(nrjP, out + NL);
}

// Round 17
// 372.311 us; speedup vs baseline: 1.0088x; 1.0088x over previous
//
#include <hip/hip_runtime.h>

#define HH 256
#define WW 256
#define NPIX (HH*WW)
#define LL 16
#define NL (NPIX*LL)
#define PP 136
#define PP2 (PP*2)
#define NBLK (NPIX/32)   // 2048

typedef _Float16 half_t;
typedef __attribute__((ext_vector_type(8))) _Float16 half8;
typedef __attribute__((ext_vector_type(4))) _Float16 half4;

// constants (double-evaluated, cast to float -- matches JAX weak-typed scalars)
static constexpr float SIGMAP_F = (float)((1.0/256.0)/(3.0+16.0)); // res/(3+l)
static constexpr float TAUU_F   = (float)((1.0/256.0)/6.0);        // res/6
static constexpr float TAU_F    = (float)(1.0/36.0);               // 1/(2+136/4)

__device__ __forceinline__ float clampf(float x, float lo, float hi){
    return fminf(fmaxf(x, lo), hi);
}
__device__ __forceinline__ half8 h8zero() {
    half8 v;
    #pragma unroll
    for (int i = 0; i < 8; ++i) v[i] = (half_t)0.0f;
    return v;
}
__device__ __forceinline__ half4 h4zero() {
    half4 v;
    #pragma unroll
    for (int i = 0; i < 4; ++i) v[i] = (half_t)0.0f;
    return v;
}

// ---------------- prox for one (pixel, z-quarter): 4 z's ---------------------
// PM 0 = it0 (all state analytically zero; reads ONLY f), PM 1 = steady.
// NOTE: this exact structure (4-z items, 260 threads) is numerically pinned:
// round 16's 2-z restructure changed FMA contraction -> flipped pixels across
// the reference's 256x snorm-projection discontinuity (absmax 0.0039->0.10).
// Do not restructure prox without re-verifying absmax.
template<int PM>
__device__ __forceinline__ void prox_q4(const float* __restrict__ f, int np, int z0,
    const half_t* __restrict__ ubOld, const half_t* __restrict__ pxOld,
    const half_t* __restrict__ ptOld, const half_t* __restrict__ msOld,
    half4& o0, half4& o1, half4& opt)
{
    int ip = np >> 8, jp = np & (WW-1);
    bool iok = (ip < HH-1), jok = (jp < WW-1);
    size_t base = (size_t)np*LL + z0;
    float fv = f[np];

    float g0c = 0.0f, g1c = 0.0f;
    half4 ubv = h4zero(), ubi = h4zero(), ubj = h4zero();
    float ubn4 = 0.0f;
    half4 ms0v = h4zero(), ms1v = h4zero();
    half4 p0v  = h4zero(), p1v  = h4zero(), ptv = h4zero();
    if (PM == 0) {
        g0c = iok ? (f[np + WW] - fv) * 256.0f : 0.0f;
        g1c = jok ? (f[np + 1]  - fv) * 256.0f : 0.0f;
    } else {
        ubv = *reinterpret_cast<const half4*>(ubOld + base);
        if (iok) ubi = *reinterpret_cast<const half4*>(ubOld + base + (size_t)WW*LL);
        if (jok) ubj = *reinterpret_cast<const half4*>(ubOld + base + LL);
        if (z0 < 12) ubn4 = (float)ubOld[base + 4];
        ms0v = *reinterpret_cast<const half4*>(msOld + base);
        ms1v = *reinterpret_cast<const half4*>(msOld + NL + base);
        p0v  = *reinterpret_cast<const half4*>(pxOld + base);
        p1v  = *reinterpret_cast<const half4*>(pxOld + NL + base);
        ptv  = *reinterpret_cast<const half4*>(ptOld + base);
    }

    #pragma unroll
    for (int e = 0; e < 4; ++e) {
        int z = z0 + e;
        float ux0, ux1, ut;
        if (PM == 0) {
            ux0 = SIGMAP_F * g0c;
            ux1 = SIGMAP_F * g1c;
            ut  = 0.0f;
        } else {
            float ub = (float)ubv[e];
            float g0 = iok ? ((float)ubi[e] - ub) * 256.0f : 0.0f;
            float g1 = jok ? ((float)ubj[e] - ub) * 256.0f : 0.0f;
            float ubn = (e < 3) ? (float)ubv[e+1] : ubn4;
            float gt = (z < LL-1) ? (ubn - ub) * 16.0f : 0.0f;
            ux0 = (float)p0v[e] + SIGMAP_F * (g0 + (float)ms0v[e]);
            ux1 = (float)p1v[e] + SIGMAP_F * (g1 + (float)ms1v[e]);
            ut  = (float)ptv[e] + SIGMAP_F * gt;
        }

        float klf = (float)(z + 1) * 0.0625f - fv;
        float pen = 0.5f * klf * klf;            // lmbda = 0.5

        float n2 = ux0*ux0 + ux1*ux1;
        float B  = 0.25f * n2 - pen;
        bool mask = ut < B;

        float px0 = ux0, px1 = ux1, ptn = ut;
        if (mask) {
            float y    = ut + pen;
            float norm = sqrtf(n2);
            float a    = 0.5f * norm;
            float b    = (2.0f/3.0f) * (1.0f - 0.5f*y);
            float v;
            if (b < 0.0f) {
                float sb  = sqrtf(-b);
                float sb3 = sb*sb*sb;
                float dd  = (a - sb3)*(a + sb3);
                if (dd < 0.0f) {
                    float ratio = clampf(a / sb3, -1.0f, 1.0f);
                    v = 2.0f * sb * cosf(acosf(ratio) * (1.0f/3.0f));
                } else {
                    float c = cbrtf(a + sqrtf(dd));
                    v = (c == 0.0f) ? 0.0f : (c - b/c);
                }
            } else {
                float dd = a*a + b*b*b;          // >= 0
                float c  = cbrtf(a + sqrtf(dd));
                v = (c == 0.0f) ? 0.0f : (c - b/c);
            }
            if (norm == 0.0f) { px0 = 0.0f; px1 = 0.0f; }
            else              { float s = 2.0f*v/norm; px0 = s*ux0; px1 = s*ux1; }
            ptn = 0.25f*(px0*px0 + px1*px1) - pen;
        }
        o0[e]  = (half_t)px0;
        o1[e]  = (half_t)px1;
        opt[e] = (half_t)ptn;
    }
}

// element access helpers (k static under unroll)
#define PH(k)  ((k) < 8 ? (float)ph0[(k)] : (float)ph1[(k)-8])
#define PPV(k) ((k) < 8 ? (float)pp0[(k)] : (float)pp1[(k)-8])

// ---------------- s & mu update for one row set ------------------------------
// mu values are PRELOADED by the caller (hoisted before the prox phase so the
// 71 MB mu stream's latency hides under prox compute + barrier).
template<int H, int MODE>
__device__ __forceinline__ void do_set(int lane,
    half8 ph0, half8 ph1, half8 pp0, half8 pp1,
    half8 mCv0, half8 mCv1, float mCT,
    half8 mOv0, half8 mOv1, float mOT,
    half_t* __restrict__ muO, size_t vb, size_t vb1, size_t tailIx,
    float* __restrict__ part)
{
    // row totals (descending start): tsA = sum p[H..15], tsB = sum p[15-H..15]
    float tsA = 0.0f, tsB = 0.0f, tpA = 0.0f, tpB = 0.0f;
    #pragma unroll
    for (int k = H; k < 16; ++k) tsA += PH(k);
    #pragma unroll
    for (int k = 15-H; k < 16; ++k) tsB += PH(k);
    if (MODE >= 1) {
        #pragma unroll
        for (int k = H; k < 16; ++k) tpA += PPV(k);
        #pragma unroll
        for (int k = 15-H; k < 16; ++k) tpB += PPV(k);
    }

    half8 muo0, muo1;
    half_t muoT = (half_t)0.0f;
    float sA = 0.0f, sB = 0.0f;
    int q = 0;

    #pragma unroll
    for (int z = 15; z >= 0; --z) {
        float m = 0.0f;
        if (z >= H) {                      // task (H, z)
            float mn;
            if (MODE == 0) {
                mn = -TAU_F * tsA;
            } else {
                float mC, mO;
                if (q < 8)       { mC=(float)mCv0[q];   mO=(float)mOv0[q]; }
                else if (q < 16) { mC=(float)mCv1[q-8]; mO=(float)mOv1[q-8]; }
                else             { mC=mCT;              mO=mOT; }
                float sxp = (mC - mO) * 36.0f + tpA;
                float mx  = sxp - (2.0f*mC - mO);
                float mo  = __shfl_xor(mx, 1);
                float snorm = sqrtf(mx*mx + mo*mo);
                if (snorm > 25.6f) mx *= 0.1f / snorm;   // nu*H ; nu/snorm
                mn = mC + TAU_F*(mx - tsA);
            }
            if (q < 8)       muo0[q]   = (half_t)mn;
            else if (q < 16) muo1[q-8] = (half_t)mn;
            else             muoT      = (half_t)mn;
            sA += mn; m += sA; ++q;
        }
        if (z >= 15-H) {                   // task (15-H, z)
            float mn;
            if (MODE == 0) {
                mn = -TAU_F * tsB;
            } else {
                float mC, mO;
                if (q < 8)       { mC=(float)mCv0[q];   mO=(float)mOv0[q]; }
                else if (q < 16) { mC=(float)mCv1[q-8]; mO=(float)mOv1[q-8]; }
                else             { mC=mCT;              mO=mOT; }
                float sxp = (mC - mO) * 36.0f + tpB;
                float mx  = sxp - (2.0f*mC - mO);
                float mo  = __shfl_xor(mx, 1);
                float snorm = sqrtf(mx*mx + mo*mo);
                if (snorm > 25.6f) mx *= 0.1f / snorm;
                mn = mC + TAU_F*(mx - tsB);
            }
            if (q < 8)       muo0[q]   = (half_t)mn;
            else if (q < 16) muo1[q-8] = (half_t)mn;
            else             muoT      = (half_t)mn;
            sB += mn; m += sB; ++q;
        }
        if (z >= H+1)    tsA -= PH(z);
        if (z >= 15-H+1) tsB -= PH(z);
        if (MODE >= 1) {
            if (z >= H+1)    tpA -= PPV(z);
            if (z >= 15-H+1) tpB -= PPV(z);
        }
        part[H*1024 + z*64 + lane] = m;
    }

    *reinterpret_cast<half8*>(&muO[vb])  = muo0;
    *reinterpret_cast<half8*>(&muO[vb1]) = muo1;
    muO[tailIx] = muoT;
}

// ---------------- fused iteration kernel -------------------------------------
// MODE: 0 = it0 (state zero; nrj partials), 1 = it1 (muO poisoned, skip read),
// 2 = steady, 3 = LAST (phase A dead: skip all mu traffic + px/pt/ms writes).
// Load schedule: mu (71 MB, the dominant stream) + pp + u issue FIRST; their
// latency hides under the prox phase (260 threads) and the barrier.
template<int MODE>
__global__ __launch_bounds__(512, 4) void k_iter(
    const float* __restrict__ f,
    const half_t* __restrict__ pxOld, half_t* __restrict__ pxCur,
    const half_t* __restrict__ ptOld, half_t* __restrict__ ptCur,
    const half_t* __restrict__ ubOld, half_t* __restrict__ ubCur,
    const half_t* __restrict__ msOld, half_t* __restrict__ msCur,
    const half_t* __restrict__ muC, half_t* __restrict__ muO,
    float* __restrict__ u, float* __restrict__ out,
    float* __restrict__ nrjPartial)
{
    __shared__ float part[(MODE <= 2) ? 8192 : 1];   // 32 KB (unused at MODE 3)
    __shared__ __align__(16) half_t lp0[64][24];     // px0: own 0..31, north 32..63
    __shared__ __align__(16) half_t lp1[33][24];     // px1: own 0..31, west 32
    __shared__ __align__(16) half_t lpt[32][24];     // pt : own
    __shared__ float wsum[8];

    int tid = threadIdx.x;
    int b   = blockIdx.x;
    int n0  = b << 5;             // first owned pixel (32 consecutive, same row)
    int i0  = n0 >> 8;
    int j0  = n0 & (WW-1);

    int wv = tid >> 6, lane = tid & 63, pix = lane >> 1, d = lane & 1;
    int n  = n0 + pix;

    // -------- hoisted loads: mu (biggest stream) + pp + u, issued first ------
    size_t setbase = (size_t)wv * 17 * 2 * NPIX;
    size_t vb     = setbase + (size_t)n*16 + (size_t)d*8;
    size_t vb1    = vb + (size_t)16*NPIX;
    size_t tailIx = setbase + (size_t)32*NPIX + (size_t)n*2 + (size_t)d;
    half8 mCv0 = h8zero(), mCv1 = h8zero(), mOv0 = h8zero(), mOv1 = h8zero();
    float mCT = 0.0f, mOT = 0.0f;
    if (MODE == 1 || MODE == 2) {
        mCv0 = *reinterpret_cast<const half8*>(&muC[vb]);
        mCv1 = *reinterpret_cast<const half8*>(&muC[vb1]);
        mCT  = (float)muC[tailIx];
    }
    if (MODE == 2) {
        mOv0 = *reinterpret_cast<const half8*>(&muO[vb]);
        mOv1 = *reinterpret_cast<const half8*>(&muO[vb1]);
        mOT  = (float)muO[tailIx];
    }
    half8 pp0 = h8zero(), pp1 = h8zero();
    if (MODE == 1 || MODE == 2) {
        const half8* ppv = reinterpret_cast<const half8*>(pxOld + (size_t)d*NL + (size_t)n*LL);
        pp0 = ppv[0]; pp1 = ppv[1];
    }
    int t  = b*512 + tid;            // global (n,z): n2 = t>>4, z = t&15
    int z  = t & (LL-1);
    int n2 = t >> 4;
    int i2 = n2 >> 8;
    int j2 = n2 & (WW-1);
    float uo = (MODE == 0) ? f[n2] : u[t];

    // -------- prox phase: 260 threads, (pixel, z-quarter) --------
    if (tid < 260) {
        int pl = tid >> 2, qf = tid & 3, z0v = qf << 2;
        int np; bool valid = true;
        if (pl < 32)      np = n0 + pl;
        else if (pl < 64) { np = n0 + (pl-32) - WW; valid = (i0 > 0); }
        else              { np = n0 - 1;            valid = (j0 > 0); }
        if (valid) {
            half4 o0, o1, opt;
            prox_q4<(MODE==0) ? 0 : 1>(f, np, z0v, ubOld, pxOld, ptOld, msOld, o0, o1, opt);
            if (pl < 64) *reinterpret_cast<half4*>(&lp0[pl][z0v]) = o0;
            if (pl < 32) {
                *reinterpret_cast<half4*>(&lp1[pl][z0v]) = o1;
                *reinterpret_cast<half4*>(&lpt[pl][z0v]) = opt;
                if (MODE <= 2) {   // next iteration consumes these
                    *reinterpret_cast<half4*>(pxCur + (size_t)np*LL + z0v)      = o0;
                    *reinterpret_cast<half4*>(pxCur + NL + (size_t)np*LL + z0v) = o1;
                    *reinterpret_cast<half4*>(ptCur + (size_t)np*LL + z0v)      = opt;
                }
            } else if (pl == 64) {
                *reinterpret_cast<half4*>(&lp1[32][z0v]) = o1;
            }
        }
    }

    __syncthreads();   // LDS px/pt visible

    // -------- phase A: s & mu (skipped entirely at MODE 3) --------
    if (MODE <= 2) {
        const half8* ls = (d == 0) ? reinterpret_cast<const half8*>(&lp0[pix][0])
                                   : reinterpret_cast<const half8*>(&lp1[pix][0]);
        half8 ph0 = ls[0], ph1 = ls[1];

        if      (wv == 0) do_set<0,MODE>(lane,ph0,ph1,pp0,pp1,mCv0,mCv1,mCT,mOv0,mOv1,mOT,muO,vb,vb1,tailIx,part);
        else if (wv == 1) do_set<1,MODE>(lane,ph0,ph1,pp0,pp1,mCv0,mCv1,mCT,mOv0,mOv1,mOT,muO,vb,vb1,tailIx,part);
        else if (wv == 2) do_set<2,MODE>(lane,ph0,ph1,pp0,pp1,mCv0,mCv1,mCT,mOv0,mOv1,mOT,muO,vb,vb1,tailIx,part);
        else if (wv == 3) do_set<3,MODE>(lane,ph0,ph1,pp0,pp1,mCv0,mCv1,mCT,mOv0,mOv1,mOT,muO,vb,vb1,tailIx,part);
        else if (wv == 4) do_set<4,MODE>(lane,ph0,ph1,pp0,pp1,mCv0,mCv1,mCT,mOv0,mOv1,mOT,muO,vb,vb1,tailIx,part);
        else if (wv == 5) do_set<5,MODE>(lane,ph0,ph1,pp0,pp1,mCv0,mCv1,mCT,mOv0,mOv1,mOT,muO,vb,vb1,tailIx,part);
        else if (wv == 6) do_set<6,MODE>(lane,ph0,ph1,pp0,pp1,mCv0,mCv1,mCT,mOv0,mOv1,mOT,muO,vb,vb1,tailIx,part);
        else              do_set<7,MODE>(lane,ph0,ph1,pp0,pp1,mCv0,mCv1,mCT,mOv0,mOv1,mOT,muO,vb,vb1,tailIx,part);

        __syncthreads();   // staged partials visible

        // -------- reduce partials over h, store fp16 musum --------
        #pragma unroll
        for (int r = 0; r < 2; ++r) {
            int z2    = (tid >> 6) + r*8;
            int inner = tid & 63;
            float s = 0.0f;
            #pragma unroll
            for (int hh = 0; hh < 8; ++hh) s += part[hh*1024 + z2*64 + inner];
            int d2 = inner & 1, pix2 = inner >> 1;
            msCur[(size_t)d2*NL + ((size_t)n0 + pix2)*LL + z2] = (half_t)s;
        }
    }

    // -------- phase B: primal u update (1 z per thread, all inputs LDS) ------
    {
        int pl2 = tid >> 4;
        float p0c = (float)lp0[pl2][z];
        float p1c = (float)lp1[pl2][z];
        float p0u = (i2 > 0) ? (float)lp0[32 + pl2][z] : 0.0f;
        float p1l = (j2 > 0) ? ((pl2 > 0) ? (float)lp1[pl2-1][z] : (float)lp1[32][z]) : 0.0f;
        float ptc = (float)lpt[pl2][z];
        float ptm = (z > 0) ? (float)lpt[pl2][z-1] : 0.0f;

        float d0 = ((i2 < HH-1) ? p0c : 0.0f) - p0u;
        float d1 = ((j2 < WW-1) ? p1c : 0.0f) - p1l;
        float dt = ((z < LL-1) ? ptc : 0.0f) - ptm;

        float Dv = uo + TAUU_F * ((d0 + d1) * 256.0f + dt * 16.0f);
        float un = clampf(Dv, 0.0f, 1.0f);
        if (z == 0)     un = 1.0f;
        if (z == LL-1)  un = 0.0f;
        if (MODE == 3) out[t] = un;      // final iteration: output directly
        else {
            u[t]     = un;
            ubCur[t] = (half_t)(2.0f*un - uo);
        }

        if (MODE == 0) {   // nrj only at it=0 (it%10==0 with repeats=10)
            float v = fabsf(un - uo);
            #pragma unroll
            for (int off = 32; off > 0; off >>= 1) v += __shfl_down(v, off);
            if ((tid & 63) == 0) wsum[wv] = v;
            __syncthreads();
            if (tid == 0) {
                float s = 0.0f;
                #pragma unroll
                for (int q2 = 0; q2 < 8; ++q2) s += wsum[q2];
                nrjPartial[b] = s;       // per-block partial; no atomics/zeroing
            }
        }
    }
}

// ---------------- tail: reduce nrj partials + scalars ------------------------
__global__ void k_final(const float* __restrict__ nrjPartial, float* __restrict__ out_tail)
{
    float s = 0.0f;
    for (int k = threadIdx.x; k < NBLK; k += 64) s += nrjPartial[k];
    #pragma unroll
    for (int off = 32; off > 0; off >>= 1) s += __shfl_down(s, off);
    if (threadIdx.x == 0) {
        out_tail[0] = s;
        out_tail[1] = s * (1.0f/1048576.0f);   // nrj / (H*W*1*l)
        out_tail[2] = 0.0f;
    }
}

extern "C" void kernel_launch(void* const* d_in, const int* in_sizes, int n_in,
                              void* d_out, int out_size, void* d_ws, size_t ws_size,
                              hipStream_t stream)
{
    const float* f = (const float*)d_in[0];
    float* out = (float*)d_out;

    char* w = (char*)d_ws;
    size_t off = 0;
    auto allocf = [&](size_t nfloats) {
        float* p = (float*)(w + off);
        off += nfloats * sizeof(float);
        return p;
    };
    auto alloch = [&](size_t nhalf) {
        half_t* p = (half_t*)(w + off);
        off += nhalf * sizeof(half_t);
        return p;
    };
    half_t* muA  = alloch((size_t)NPIX * PP2);   // 35.7 MB
    half_t* muB  = alloch((size_t)NPIX * PP2);   // 35.7 MB
    half_t* msA  = alloch(2*(size_t)NL);         // 4.2 MB
    half_t* msB  = alloch(2*(size_t)NL);
    half_t* pxA  = alloch(2*(size_t)NL);
    half_t* pxB  = alloch(2*(size_t)NL);
    half_t* ptA  = alloch((size_t)NL);           // 2.1 MB
    half_t* ptB  = alloch((size_t)NL);
    half_t* ubA  = alloch((size_t)NL);
    half_t* ubB  = alloch((size_t)NL);
    float*  u    = allocf((size_t)NL);           // 4.2 MB
    float*  nrjP = allocf(NBLK);
    (void)ws_size; (void)in_sizes; (void)n_in; (void)out_size;

    // No memset/init: it=0 fully specialized (MODE 0 reads only f); it=1 skips
    // the muO read (poisoned buffer fully overwritten at it=0/1); all other
    // buffers' first access is a write. nrj via per-block partials.
    half_t *pxO = pxA, *pxC = pxB;
    half_t *ptO = ptA, *ptC = ptB;
    half_t *ubO = ubA, *ubC = ubB;
    half_t *msO = msA, *msC = msB;
    half_t *mC  = muA, *mO  = muB;
    for (int it = 0; it < 10; ++it) {
        if (it == 0)
            k_iter<0><<<NBLK, 512, 0, stream>>>(f, pxO, pxC, ptO, ptC, ubO, ubC,
                                                msO, msC, mC, mO, u, out, nrjP);
        else if (it == 1)
            k_iter<1><<<NBLK, 512, 0, stream>>>(f, pxO, pxC, ptO, ptC, ubO, ubC,
                                                msO, msC, mC, mO, u, out, nrjP);
        else if (it < 9)
            k_iter<2><<<NBLK, 512, 0, stream>>>(f, pxO, pxC, ptO, ptC, ubO, ubC,
                                                msO, msC, mC, mO, u, out, nrjP);
        else
            k_iter<3><<<NBLK, 512, 0, stream>>>(f, pxO, pxC, ptO, ptC, ubO, ubC,
                                                msO, msC, mC, mO, u, out, nrjP);
        { half_t* tmp = pxO; pxO = pxC; pxC = tmp; }
        { half_t* tmp = ptO; ptO = ptC; ptC = tmp; }
        { half_t* tmp = ubO; ubO = ubC; ubC = tmp; }
        { half_t* tmp = msO; msO = msC; msC = tmp; }
        { half_t* tmp = mC;  mC  = mO;  mO  = tmp; }   // mO-buffer holds mu_k
    }

    k_final<<<1, 64, 0, stream>>>(nrjP, out + NL);
}